// Round 1
// baseline (1418.858 us; speedup 1.0000x reference)
//
#include <hip/hip_runtime.h>
#include <math.h>

#define NB 4096
#define DX 1024
#define DZv 128
#define KNN 10
#define STRIPS 8
#define SLEN (NB / STRIPS) /* 512 */

// ---------------- row sum of squares ----------------
__global__ __launch_bounds__(256) void k_rowsq(const float* __restrict__ a,
                                               float* __restrict__ out, int D) {
  int row = blockIdx.x;
  const float* p = a + (size_t)row * D;
  float s = 0.f;
  for (int d = threadIdx.x; d < D; d += 256) { float v = p[d]; s = fmaf(v, v, s); }
#pragma unroll
  for (int m = 32; m; m >>= 1) s += __shfl_xor(s, m);
  __shared__ float red[4];
  int w = threadIdx.x >> 6;
  if ((threadIdx.x & 63) == 0) red[w] = s;
  __syncthreads();
  if (threadIdx.x == 0) out[row] = red[0] + red[1] + red[2] + red[3];
}

// ---------------- kNN: per-strip top-10 (self excluded) ----------------
__global__ __launch_bounds__(256) void k_knn(const float* __restrict__ x,
                                             const float* __restrict__ sqx,
                                             float* __restrict__ cand_d,
                                             int* __restrict__ cand_i) {
  __shared__ float As[32][68];   // transposed: As[k][row]
  __shared__ float Bs[32][68];
  __shared__ float Cs[64][65];
  __shared__ float td[64][KNN];
  __shared__ int   ti[64][KNN];

  const int strip = blockIdx.x;
  const int i0 = blockIdx.y * 64;
  const int tid = threadIdx.x;
  const int tr = tid >> 4, tc = tid & 15;
  int cnt = 0;

  for (int jt = 0; jt < SLEN / 64; ++jt) {
    const int j0 = strip * SLEN + jt * 64;
    float acc[4][4] = {};
    for (int kc = 0; kc < DX; kc += 32) {
      __syncthreads();
#pragma unroll
      for (int l = 0; l < 8; ++l) {
        int e = tid + l * 256;
        int r = e >> 5, c = e & 31;
        As[c][r] = x[(size_t)(i0 + r) * DX + kc + c];
        Bs[c][r] = x[(size_t)(j0 + r) * DX + kc + c];
      }
      __syncthreads();
#pragma unroll
      for (int k = 0; k < 32; ++k) {
        float4 a4 = *(const float4*)&As[k][tr * 4];
        float4 b4 = *(const float4*)&Bs[k][tc * 4];
        float av[4] = {a4.x, a4.y, a4.z, a4.w};
        float bv[4] = {b4.x, b4.y, b4.z, b4.w};
#pragma unroll
        for (int a = 0; a < 4; ++a)
#pragma unroll
          for (int b = 0; b < 4; ++b) acc[a][b] = fmaf(av[a], bv[b], acc[a][b]);
      }
    }
    __syncthreads();
#pragma unroll
    for (int a = 0; a < 4; ++a)
#pragma unroll
      for (int b = 0; b < 4; ++b) {
        int gi = i0 + tr * 4 + a, gj = j0 + tc * 4 + b;
        float v = sqx[gi] + sqx[gj] - 2.f * acc[a][b];
        Cs[tr * 4 + a][tc * 4 + b] = (gi == gj) ? 3.0e38f : v;
      }
    __syncthreads();
    if (tid < 64) {
      const int r = tid;
      for (int c = 0; c < 64; ++c) {
        float v = Cs[r][c];
        if (cnt < KNN) {
          int p = cnt++;
          while (p > 0 && td[r][p - 1] > v) {
            td[r][p] = td[r][p - 1]; ti[r][p] = ti[r][p - 1]; --p;
          }
          td[r][p] = v; ti[r][p] = j0 + c;
        } else if (v < td[r][KNN - 1]) {
          int p = KNN - 1;
          while (p > 0 && td[r][p - 1] > v) {
            td[r][p] = td[r][p - 1]; ti[r][p] = ti[r][p - 1]; --p;
          }
          td[r][p] = v; ti[r][p] = j0 + c;
        }
      }
    }
    __syncthreads();
  }
  if (tid < 64) {
    int row = i0 + tid;
#pragma unroll
    for (int l = 0; l < KNN; ++l) {
      cand_d[((size_t)row * STRIPS + strip) * KNN + l] = td[tid][l];
      cand_i[((size_t)row * STRIPS + strip) * KNN + l] = ti[tid][l];
    }
  }
}

// ---------------- merge strip candidates -> global top-10 ----------------
__global__ __launch_bounds__(64) void k_merge(const float* __restrict__ cand_d,
                                              const int* __restrict__ cand_i,
                                              int* __restrict__ knn) {
  __shared__ float td[64][KNN];
  __shared__ int   ti[64][KNN];
  int t = threadIdx.x;
  int row = blockIdx.x * 64 + t;
  int cnt = 0;
  for (int s = 0; s < STRIPS; ++s)
    for (int l = 0; l < KNN; ++l) {
      float v = cand_d[((size_t)row * STRIPS + s) * KNN + l];
      int j = cand_i[((size_t)row * STRIPS + s) * KNN + l];
      if (cnt < KNN) {
        int p = cnt++;
        while (p > 0 && td[t][p - 1] > v) {
          td[t][p] = td[t][p - 1]; ti[t][p] = ti[t][p - 1]; --p;
        }
        td[t][p] = v; ti[t][p] = j;
      } else if (v < td[t][KNN - 1]) {
        int p = KNN - 1;
        while (p > 0 && td[t][p - 1] > v) {
          td[t][p] = td[t][p - 1]; ti[t][p] = ti[t][p - 1]; --p;
        }
        td[t][p] = v; ti[t][p] = j;
      }
    }
  for (int l = 0; l < KNN; ++l) knn[row * KNN + l] = ti[t][l];
}

// ---------------- Gram matrix of centered neighbors (one wave / point) ----
__global__ __launch_bounds__(64) void k_gram(const float* __restrict__ x,
                                             const int* __restrict__ knn,
                                             float* __restrict__ G) {
  const int pt = blockIdx.x;
  const int lane = threadIdx.x;
  int nb[KNN];
#pragma unroll
  for (int a = 0; a < KNN; ++a) nb[a] = knn[pt * KNN + a];
  float P[55];
  float U[KNN];
  float q = 0.f;
#pragma unroll
  for (int c = 0; c < 55; ++c) P[c] = 0.f;
#pragma unroll
  for (int a = 0; a < KNN; ++a) U[a] = 0.f;
  for (int d = lane; d < DX; d += 64) {
    float n[KNN];
#pragma unroll
    for (int a = 0; a < KNN; ++a) n[a] = x[(size_t)nb[a] * DX + d];
    float m = 0.f;
#pragma unroll
    for (int a = 0; a < KNN; ++a) m += n[a];
    m *= 0.1f;
    q = fmaf(m, m, q);
#pragma unroll
    for (int a = 0; a < KNN; ++a) U[a] = fmaf(n[a], m, U[a]);
    int c = 0;
#pragma unroll
    for (int a = 0; a < KNN; ++a)
#pragma unroll
      for (int b = a; b < KNN; ++b) { P[c] = fmaf(n[a], n[b], P[c]); ++c; }
  }
#pragma unroll
  for (int c = 0; c < 55; ++c)
#pragma unroll
    for (int m2 = 32; m2; m2 >>= 1) P[c] += __shfl_xor(P[c], m2);
#pragma unroll
  for (int a = 0; a < KNN; ++a)
#pragma unroll
    for (int m2 = 32; m2; m2 >>= 1) U[a] += __shfl_xor(U[a], m2);
#pragma unroll
  for (int m2 = 32; m2; m2 >>= 1) q += __shfl_xor(q, m2);
  if (lane == 0) {
    int c = 0;
    for (int a = 0; a < KNN; ++a)
      for (int b = a; b < KNN; ++b) { G[(size_t)pt * 55 + c] = P[c] - U[a] - U[b] + q; ++c; }
  }
}

// ---------------- Jacobi eigenvalues of 10x10, curvature -----------------
#define JST 101
__global__ __launch_bounds__(64) void k_jacobi(const float* __restrict__ G,
                                               float* __restrict__ curv) {
  __shared__ float Ash[64 * JST];
  const int t = threadIdx.x;
  const int pt = blockIdx.x * 64 + t;
  float* M = &Ash[t * JST];
  {
    int c = 0;
    for (int a = 0; a < KNN; ++a)
      for (int b = a; b < KNN; ++b) {
        float v = G[(size_t)pt * 55 + c]; ++c;
        M[a * KNN + b] = v; M[b * KNN + a] = v;
      }
  }
  for (int sweep = 0; sweep < 10; ++sweep) {
    for (int pp = 0; pp < KNN - 1; ++pp)
      for (int qq = pp + 1; qq < KNN; ++qq) {
        float apq = M[pp * KNN + qq];
        if (fabsf(apq) < 1e-28f) continue;
        float app = M[pp * KNN + pp], aqq = M[qq * KNN + qq];
        float theta = (aqq - app) / (2.f * apq);
        float den = fabsf(theta) + sqrtf(fmaf(theta, theta, 1.f));
        float tt = 1.f / den;
        if (theta < 0.f) tt = -tt;
        float cc = 1.f / sqrtf(fmaf(tt, tt, 1.f));
        float ss = tt * cc;
        for (int r = 0; r < KNN; ++r) {
          float arp = M[r * KNN + pp], arq = M[r * KNN + qq];
          M[r * KNN + pp] = cc * arp - ss * arq;
          M[r * KNN + qq] = ss * arp + cc * arq;
        }
        for (int r = 0; r < KNN; ++r) {
          float apr = M[pp * KNN + r], aqr = M[qq * KNN + r];
          M[pp * KNN + r] = cc * apr - ss * aqr;
          M[qq * KNN + r] = ss * apr + cc * aqr;
        }
      }
  }
  float lmax = 0.f, ssum = 0.f;
  for (int a = 0; a < KNN; ++a) {
    float l = fmaxf(M[a * KNN + a], 0.f);
    lmax = fmaxf(lmax, l);
    ssum += sqrtf(l);
  }
  curv[pt] = 1.f - sqrtf(lmax) / (ssum + 1e-8f);
}

// ---------------- fused z/ref upper-triangle pass ----------------
__global__ __launch_bounds__(256) void k_zr(const float* __restrict__ z,
                                            const float* __restrict__ rfm,
                                            const float* __restrict__ sqz,
                                            const float* __restrict__ sqr,
                                            const float* __restrict__ curv,
                                            double* __restrict__ pS,
                                            float* __restrict__ pM) {
  __shared__ float As[32][68];
  __shared__ float Bs[32][68];
  const int t = blockIdx.x;
  int ib = 0, base = 0;
  while (base + (64 - ib) <= t) { base += 64 - ib; ++ib; }
  int jb = ib + (t - base);
  const int i0 = ib * 64, j0 = jb * 64;
  const int tid = threadIdx.x;
  const int tr = tid >> 4, tc = tid & 15;
  float zacc[4][4] = {}, racc[4][4] = {};

  for (int kc = 0; kc < DZv; kc += 32) {
    __syncthreads();
#pragma unroll
    for (int l = 0; l < 8; ++l) {
      int e = tid + l * 256;
      int r = e >> 5, c = e & 31;
      As[c][r] = z[(size_t)(i0 + r) * DZv + kc + c];
      Bs[c][r] = z[(size_t)(j0 + r) * DZv + kc + c];
    }
    __syncthreads();
#pragma unroll
    for (int k = 0; k < 32; ++k) {
      float4 a4 = *(const float4*)&As[k][tr * 4];
      float4 b4 = *(const float4*)&Bs[k][tc * 4];
      float av[4] = {a4.x, a4.y, a4.z, a4.w};
      float bv[4] = {b4.x, b4.y, b4.z, b4.w};
#pragma unroll
      for (int a = 0; a < 4; ++a)
#pragma unroll
        for (int b = 0; b < 4; ++b) zacc[a][b] = fmaf(av[a], bv[b], zacc[a][b]);
    }
  }
  for (int kc = 0; kc < DZv; kc += 32) {
    __syncthreads();
#pragma unroll
    for (int l = 0; l < 8; ++l) {
      int e = tid + l * 256;
      int r = e >> 5, c = e & 31;
      As[c][r] = rfm[(size_t)(i0 + r) * DZv + kc + c];
      Bs[c][r] = rfm[(size_t)(j0 + r) * DZv + kc + c];
    }
    __syncthreads();
#pragma unroll
    for (int k = 0; k < 32; ++k) {
      float4 a4 = *(const float4*)&As[k][tr * 4];
      float4 b4 = *(const float4*)&Bs[k][tc * 4];
      float av[4] = {a4.x, a4.y, a4.z, a4.w};
      float bv[4] = {b4.x, b4.y, b4.z, b4.w};
#pragma unroll
      for (int a = 0; a < 4; ++a)
#pragma unroll
        for (int b = 0; b < 4; ++b) racc[a][b] = fmaf(av[a], bv[b], racc[a][b]);
    }
  }

  double s1 = 0, s2 = 0, s3 = 0;
  float mz = 0.f, mr = 0.f;
#pragma unroll
  for (int a = 0; a < 4; ++a) {
    int gi = i0 + tr * 4 + a;
    float czi = curv[gi], szi = sqz[gi], sri = sqr[gi];
#pragma unroll
    for (int b = 0; b < 4; ++b) {
      int gj = j0 + tc * 4 + b;
      if (gj <= gi) continue;
      float z2 = fmaxf(szi + sqz[gj] - 2.f * zacc[a][b], 0.f);
      float r2 = fmaxf(sri + sqr[gj] - 2.f * racc[a][b], 0.f);
      float w = fmaxf(1.f - fmaxf(czi, curv[gj]), 0.1f);
      s1 += (double)(w * z2);
      s3 += (double)(w * r2);
      s2 += (double)(w * sqrtf(z2 * r2));
      mz = fmaxf(mz, z2);
      mr = fmaxf(mr, r2);
    }
  }
#pragma unroll
  for (int m = 32; m; m >>= 1) {
    s1 += __shfl_xor(s1, m);
    s2 += __shfl_xor(s2, m);
    s3 += __shfl_xor(s3, m);
    mz = fmaxf(mz, __shfl_xor(mz, m));
    mr = fmaxf(mr, __shfl_xor(mr, m));
  }
  __shared__ double rd[4][3];
  __shared__ float rf2[4][2];
  int w = tid >> 6;
  if ((tid & 63) == 0) { rd[w][0] = s1; rd[w][1] = s2; rd[w][2] = s3; rf2[w][0] = mz; rf2[w][1] = mr; }
  __syncthreads();
  if (tid == 0) {
    double a = 0, b = 0, c = 0; float d = 0.f, e = 0.f;
    for (int i = 0; i < 4; ++i) {
      a += rd[i][0]; b += rd[i][1]; c += rd[i][2];
      d = fmaxf(d, rf2[i][0]); e = fmaxf(e, rf2[i][1]);
    }
    pS[(size_t)t * 3 + 0] = a; pS[(size_t)t * 3 + 1] = b; pS[(size_t)t * 3 + 2] = c;
    pM[(size_t)t * 2 + 0] = d; pM[(size_t)t * 2 + 1] = e;
  }
}

// ---------------- final combine ----------------
__global__ __launch_bounds__(256) void k_final(const double* __restrict__ pS,
                                               const float* __restrict__ pM,
                                               int nb, float* __restrict__ out) {
  int tid = threadIdx.x;
  double s1 = 0, s2 = 0, s3 = 0; float mz = 0.f, mr = 0.f;
  for (int i = tid; i < nb; i += 256) {
    s1 += pS[(size_t)i * 3 + 0]; s2 += pS[(size_t)i * 3 + 1]; s3 += pS[(size_t)i * 3 + 2];
    mz = fmaxf(mz, pM[(size_t)i * 2 + 0]); mr = fmaxf(mr, pM[(size_t)i * 2 + 1]);
  }
#pragma unroll
  for (int m = 32; m; m >>= 1) {
    s1 += __shfl_xor(s1, m); s2 += __shfl_xor(s2, m); s3 += __shfl_xor(s3, m);
    mz = fmaxf(mz, __shfl_xor(mz, m)); mr = fmaxf(mr, __shfl_xor(mr, m));
  }
  __shared__ double rd[4][3];
  __shared__ float rf2[4][2];
  int w = tid >> 6;
  if ((tid & 63) == 0) { rd[w][0] = s1; rd[w][1] = s2; rd[w][2] = s3; rf2[w][0] = mz; rf2[w][1] = mr; }
  __syncthreads();
  if (tid == 0) {
    double a = 0, b = 0, c = 0; float d = 0.f, e = 0.f;
    for (int i = 0; i < 4; ++i) {
      a += rd[i][0]; b += rd[i][1]; c += rd[i][2];
      d = fmaxf(d, rf2[i][0]); e = fmaxf(e, rf2[i][1]);
    }
    double zm = sqrt((double)d) + 1e-8;
    double rm = sqrt((double)e) + 1e-8;
    double total = a / (zm * zm) - 2.0 * b / (zm * rm) + c / (rm * rm);
    double npairs = (double)NB * (double)(NB - 1) / 2.0;
    out[0] = (float)(total / npairs);
  }
}

extern "C" void kernel_launch(void* const* d_in, const int* in_sizes, int n_in,
                              void* d_out, int out_size, void* d_ws, size_t ws_size,
                              hipStream_t stream) {
  const float* z = (const float*)d_in[0];
  const float* rfm = (const float*)d_in[1];
  const float* x = (const float*)d_in[2];
  float* out = (float*)d_out;
  char* w = (char*)d_ws;

  float* sqx    = (float*)(w + 0);
  float* sqz    = (float*)(w + 16384);
  float* sqr    = (float*)(w + 32768);
  float* curv   = (float*)(w + 49152);
  int*   knn    = (int*)(w + 65536);
  float* cand_d = (float*)(w + 229376);
  int*   cand_i = (int*)(w + 1540096);
  float* G      = (float*)(w + 2850816);
  double* pS    = (double*)(w + 3751936);
  float* pM     = (float*)(w + 3801856);

  k_rowsq<<<NB, 256, 0, stream>>>(x, sqx, DX);
  k_rowsq<<<NB, 256, 0, stream>>>(z, sqz, DZv);
  k_rowsq<<<NB, 256, 0, stream>>>(rfm, sqr, DZv);
  k_knn<<<dim3(STRIPS, NB / 64), 256, 0, stream>>>(x, sqx, cand_d, cand_i);
  k_merge<<<NB / 64, 64, 0, stream>>>(cand_d, cand_i, knn);
  k_gram<<<NB, 64, 0, stream>>>(x, knn, G);
  k_jacobi<<<NB / 64, 64, 0, stream>>>(G, curv);
  k_zr<<<2080, 256, 0, stream>>>(z, rfm, sqz, sqr, curv, pS, pM);
  k_final<<<1, 256, 0, stream>>>(pS, pM, 2080, out);
}

// Round 2
// 755.212 us; speedup vs baseline: 1.8788x; 1.8788x over previous
//
#include <hip/hip_runtime.h>
#include <math.h>

#define NB 4096
#define DX 1024
#define DZ 128
#define KNN 10
#define STR 16
#define SLEN (NB / STR) /* 256 */

typedef short short8v __attribute__((ext_vector_type(8)));
typedef float f32x4 __attribute__((ext_vector_type(4)));

#define MFMA16(a, b, c) __builtin_amdgcn_mfma_f32_16x16x32_bf16((a), (b), (c), 0, 0, 0)

__device__ __forceinline__ ushort f2bf(float f) {
  unsigned u = __float_as_uint(f);
  u += 0x7FFFu + ((u >> 16) & 1u);
  return (ushort)(u >> 16);
}
__device__ __forceinline__ float bf2f(ushort h) {
  return __uint_as_float(((unsigned)h) << 16);
}

// swizzled LDS fragment load: 8 contiguous bf16 at [row][fg*8]
__device__ __forceinline__ short8v frag_ld(const ushort* base, int row, int fg) {
  int off = (row << 6) + (fg << 4);
  off ^= (row & 7) << 4;
  return *(const short8v*)((const char*)base + off);
}

// ---------------- row sum of squares ----------------
__global__ __launch_bounds__(256) void k_rowsq(const float* __restrict__ a,
                                               float* __restrict__ out, int D) {
  int row = blockIdx.x;
  const float* p = a + (size_t)row * D;
  float s = 0.f;
  for (int d = threadIdx.x; d < D; d += 256) { float v = p[d]; s = fmaf(v, v, s); }
#pragma unroll
  for (int m = 32; m; m >>= 1) s += __shfl_xor(s, m);
  __shared__ float red[4];
  int w = threadIdx.x >> 6;
  if ((threadIdx.x & 63) == 0) red[w] = s;
  __syncthreads();
  if (threadIdx.x == 0) out[row] = red[0] + red[1] + red[2] + red[3];
}

// ---------------- split x into bf16 hi/lo ----------------
__global__ __launch_bounds__(256) void k_split(const float* __restrict__ a,
                                               ushort* __restrict__ hi,
                                               ushort* __restrict__ lo) {
  int idx = blockIdx.x * 256 + threadIdx.x;
  float4 v = ((const float4*)a)[idx];
  float vv[4] = {v.x, v.y, v.z, v.w};
  ushort h[4], l[4];
#pragma unroll
  for (int e = 0; e < 4; ++e) {
    h[e] = f2bf(vv[e]);
    l[e] = f2bf(vv[e] - bf2f(h[e]));
  }
  ushort4 hv; hv.x = h[0]; hv.y = h[1]; hv.z = h[2]; hv.w = h[3];
  ushort4 lv; lv.x = l[0]; lv.y = l[1]; lv.z = l[2]; lv.w = l[3];
  ((ushort4*)hi)[idx] = hv;
  ((ushort4*)lo)[idx] = lv;
}

// ---------------- kNN via MFMA: 128x128 tiles, strip top-10 ----------------
struct SmemKNN {
  union {
    struct { ushort Ah[4096], Al[4096], Bh[4096], Bl[4096]; } s;  // 32 KB
    float D[128 * 129];                                           // 66 KB
  } u;
  float td[128][KNN];
  int   ti[128][KNN];
};

template<int PRE>
__global__ __launch_bounds__(256, 2) void k_knn(const float* __restrict__ x,
                                                const ushort* __restrict__ xh,
                                                const ushort* __restrict__ xl,
                                                const float* __restrict__ sqx,
                                                float* __restrict__ cand_d,
                                                int* __restrict__ cand_i) {
  __shared__ SmemKNN sm;
  const int strip = blockIdx.x;
  const int i0 = blockIdx.y * 128;
  const int tid = threadIdx.x;
  const int lane = tid & 63, wv = tid >> 6;
  const int wr = wv >> 1, wc = wv & 1;
  const int fr = lane & 15, fg = lane >> 4;

  for (int idx = tid; idx < 128 * KNN; idx += 256) {
    ((float*)sm.td)[idx] = 3.0e38f;
    ((int*)sm.ti)[idx] = 0;
  }

  for (int jt = 0; jt < SLEN / 128; ++jt) {
    const int j0 = strip * SLEN + jt * 128;
    f32x4 acc[4][4];
    const f32x4 zv = {0.f, 0.f, 0.f, 0.f};
#pragma unroll
    for (int m = 0; m < 4; ++m)
#pragma unroll
      for (int n = 0; n < 4; ++n) acc[m][n] = zv;

    for (int kc = 0; kc < DX; kc += 32) {
      __syncthreads();
      if (PRE) {
#pragma unroll
        for (int l = 0; l < 2; ++l) {
          int idx = tid + l * 256;            // 0..511
          int row = idx >> 2, c8 = idx & 3;   // 8 bf16 per c8
          int off = (row << 6) + (c8 << 4);
          off ^= (row & 7) << 4;
          size_t ga = (size_t)(i0 + row) * DX + kc + c8 * 8;
          size_t gb = (size_t)(j0 + row) * DX + kc + c8 * 8;
          *(uint4*)((char*)sm.u.s.Ah + off) = *(const uint4*)(xh + ga);
          *(uint4*)((char*)sm.u.s.Al + off) = *(const uint4*)(xl + ga);
          *(uint4*)((char*)sm.u.s.Bh + off) = *(const uint4*)(xh + gb);
          *(uint4*)((char*)sm.u.s.Bl + off) = *(const uint4*)(xl + gb);
        }
      } else {
#pragma unroll
        for (int l = 0; l < 4; ++l) {
          int idx = tid + l * 256;            // 0..1023
          int row = idx >> 3, c4 = idx & 7;
          int off = (row << 6) + (c4 << 3);
          off ^= (row & 7) << 4;
          float4 va = *(const float4*)&x[(size_t)(i0 + row) * DX + kc + c4 * 4];
          float4 vb = *(const float4*)&x[(size_t)(j0 + row) * DX + kc + c4 * 4];
          float av[4] = {va.x, va.y, va.z, va.w};
          float bv[4] = {vb.x, vb.y, vb.z, vb.w};
          ushort ah4[4], al4[4], bh4[4], bl4[4];
#pragma unroll
          for (int e = 0; e < 4; ++e) {
            ah4[e] = f2bf(av[e]); al4[e] = f2bf(av[e] - bf2f(ah4[e]));
            bh4[e] = f2bf(bv[e]); bl4[e] = f2bf(bv[e] - bf2f(bh4[e]));
          }
          uint2 p;
          p.x = (unsigned)ah4[0] | ((unsigned)ah4[1] << 16);
          p.y = (unsigned)ah4[2] | ((unsigned)ah4[3] << 16);
          *(uint2*)((char*)sm.u.s.Ah + off) = p;
          p.x = (unsigned)al4[0] | ((unsigned)al4[1] << 16);
          p.y = (unsigned)al4[2] | ((unsigned)al4[3] << 16);
          *(uint2*)((char*)sm.u.s.Al + off) = p;
          p.x = (unsigned)bh4[0] | ((unsigned)bh4[1] << 16);
          p.y = (unsigned)bh4[2] | ((unsigned)bh4[3] << 16);
          *(uint2*)((char*)sm.u.s.Bh + off) = p;
          p.x = (unsigned)bl4[0] | ((unsigned)bl4[1] << 16);
          p.y = (unsigned)bl4[2] | ((unsigned)bl4[3] << 16);
          *(uint2*)((char*)sm.u.s.Bl + off) = p;
        }
      }
      __syncthreads();
      short8v fah[4], fal[4];
#pragma unroll
      for (int m = 0; m < 4; ++m) {
        int r = wr * 64 + m * 16 + fr;
        fah[m] = frag_ld(sm.u.s.Ah, r, fg);
        fal[m] = frag_ld(sm.u.s.Al, r, fg);
      }
#pragma unroll
      for (int n = 0; n < 4; ++n) {
        int r = wc * 64 + n * 16 + fr;
        short8v fbh = frag_ld(sm.u.s.Bh, r, fg);
        short8v fbl = frag_ld(sm.u.s.Bl, r, fg);
#pragma unroll
        for (int m = 0; m < 4; ++m) {
          acc[m][n] = MFMA16(fah[m], fbh, acc[m][n]);
          acc[m][n] = MFMA16(fah[m], fbl, acc[m][n]);
          acc[m][n] = MFMA16(fal[m], fbh, acc[m][n]);
        }
      }
    }
    __syncthreads();
#pragma unroll
    for (int m = 0; m < 4; ++m)
#pragma unroll
      for (int n = 0; n < 4; ++n)
#pragma unroll
        for (int r = 0; r < 4; ++r) {
          int rl = wr * 64 + m * 16 + fg * 4 + r;
          int cl = wc * 64 + n * 16 + fr;
          int gi = i0 + rl, gj = j0 + cl;
          float v = sqx[gi] + sqx[gj] - 2.f * acc[m][n][r];
          sm.u.D[rl * 129 + cl] = (gi == gj) ? 3.0e38f : v;
        }
    __syncthreads();
    if (tid < 128) {
      for (int c = 0; c < 128; ++c) {
        float v = sm.u.D[tid * 129 + c];
        if (v < sm.td[tid][KNN - 1]) {
          int p = KNN - 1;
          while (p > 0 && sm.td[tid][p - 1] > v) {
            sm.td[tid][p] = sm.td[tid][p - 1];
            sm.ti[tid][p] = sm.ti[tid][p - 1];
            --p;
          }
          sm.td[tid][p] = v;
          sm.ti[tid][p] = j0 + c;
        }
      }
    }
  }
  __syncthreads();
  if (tid < 128) {
    int row = i0 + tid;
#pragma unroll
    for (int l = 0; l < KNN; ++l) {
      cand_d[((size_t)row * STR + strip) * KNN + l] = sm.td[tid][l];
      cand_i[((size_t)row * STR + strip) * KNN + l] = sm.ti[tid][l];
    }
  }
}

// ---------------- merge strip candidates -> global top-10 ----------------
__global__ __launch_bounds__(64) void k_merge(const float* __restrict__ cand_d,
                                              const int* __restrict__ cand_i,
                                              int* __restrict__ knn) {
  __shared__ float td[64][KNN];
  __shared__ int   ti[64][KNN];
  int t = threadIdx.x;
  int row = blockIdx.x * 64 + t;
  for (int l = 0; l < KNN; ++l) { td[t][l] = 3.0e38f; ti[t][l] = 0; }
  for (int s = 0; s < STR; ++s)
    for (int l = 0; l < KNN; ++l) {
      float v = cand_d[((size_t)row * STR + s) * KNN + l];
      int j = cand_i[((size_t)row * STR + s) * KNN + l];
      if (v < td[t][KNN - 1]) {
        int p = KNN - 1;
        while (p > 0 && td[t][p - 1] > v) {
          td[t][p] = td[t][p - 1]; ti[t][p] = ti[t][p - 1]; --p;
        }
        td[t][p] = v; ti[t][p] = j;
      }
    }
  for (int l = 0; l < KNN; ++l) knn[row * KNN + l] = ti[t][l];
}

// ---------------- Gram matrix of centered neighbors (one wave / point) ----
__global__ __launch_bounds__(64) void k_gram(const float* __restrict__ x,
                                             const int* __restrict__ knn,
                                             float* __restrict__ G) {
  const int pt = blockIdx.x;
  const int lane = threadIdx.x;
  int nb[KNN];
#pragma unroll
  for (int a = 0; a < KNN; ++a) nb[a] = knn[pt * KNN + a];
  float P[55];
  float U[KNN];
  float q = 0.f;
#pragma unroll
  for (int c = 0; c < 55; ++c) P[c] = 0.f;
#pragma unroll
  for (int a = 0; a < KNN; ++a) U[a] = 0.f;
  for (int d = lane; d < DX; d += 64) {
    float n[KNN];
#pragma unroll
    for (int a = 0; a < KNN; ++a) n[a] = x[(size_t)nb[a] * DX + d];
    float m = 0.f;
#pragma unroll
    for (int a = 0; a < KNN; ++a) m += n[a];
    m *= 0.1f;
    q = fmaf(m, m, q);
#pragma unroll
    for (int a = 0; a < KNN; ++a) U[a] = fmaf(n[a], m, U[a]);
    int c = 0;
#pragma unroll
    for (int a = 0; a < KNN; ++a)
#pragma unroll
      for (int b = a; b < KNN; ++b) { P[c] = fmaf(n[a], n[b], P[c]); ++c; }
  }
#pragma unroll
  for (int c = 0; c < 55; ++c)
#pragma unroll
    for (int m2 = 32; m2; m2 >>= 1) P[c] += __shfl_xor(P[c], m2);
#pragma unroll
  for (int a = 0; a < KNN; ++a)
#pragma unroll
    for (int m2 = 32; m2; m2 >>= 1) U[a] += __shfl_xor(U[a], m2);
#pragma unroll
  for (int m2 = 32; m2; m2 >>= 1) q += __shfl_xor(q, m2);
  if (lane == 0) {
    int c = 0;
    for (int a = 0; a < KNN; ++a)
      for (int b = a; b < KNN; ++b) { G[(size_t)pt * 55 + c] = P[c] - U[a] - U[b] + q; ++c; }
  }
}

// ---------------- Jacobi eigenvalues of 10x10, curvature -----------------
#define JST 101
__global__ __launch_bounds__(64) void k_jacobi(const float* __restrict__ G,
                                               float* __restrict__ curv) {
  __shared__ float Ash[64 * JST];
  const int t = threadIdx.x;
  const int pt = blockIdx.x * 64 + t;
  float* M = &Ash[t * JST];
  {
    int c = 0;
    for (int a = 0; a < KNN; ++a)
      for (int b = a; b < KNN; ++b) {
        float v = G[(size_t)pt * 55 + c]; ++c;
        M[a * KNN + b] = v; M[b * KNN + a] = v;
      }
  }
  for (int sweep = 0; sweep < 10; ++sweep) {
    for (int pp = 0; pp < KNN - 1; ++pp)
      for (int qq = pp + 1; qq < KNN; ++qq) {
        float apq = M[pp * KNN + qq];
        if (fabsf(apq) < 1e-28f) continue;
        float app = M[pp * KNN + pp], aqq = M[qq * KNN + qq];
        float theta = (aqq - app) / (2.f * apq);
        float den = fabsf(theta) + sqrtf(fmaf(theta, theta, 1.f));
        float tt = 1.f / den;
        if (theta < 0.f) tt = -tt;
        float cc = 1.f / sqrtf(fmaf(tt, tt, 1.f));
        float ss = tt * cc;
        for (int r = 0; r < KNN; ++r) {
          float arp = M[r * KNN + pp], arq = M[r * KNN + qq];
          M[r * KNN + pp] = cc * arp - ss * arq;
          M[r * KNN + qq] = ss * arp + cc * arq;
        }
        for (int r = 0; r < KNN; ++r) {
          float apr = M[pp * KNN + r], aqr = M[qq * KNN + r];
          M[pp * KNN + r] = cc * apr - ss * aqr;
          M[qq * KNN + r] = ss * apr + cc * aqr;
        }
      }
  }
  float lmax = 0.f, ssum = 0.f;
  for (int a = 0; a < KNN; ++a) {
    float l = fmaxf(M[a * KNN + a], 0.f);
    lmax = fmaxf(lmax, l);
    ssum += sqrtf(l);
  }
  curv[pt] = 1.f - sqrtf(lmax) / (ssum + 1e-8f);
}

// ---------------- fused z/ref upper-triangle pass (MFMA) ----------------
__global__ __launch_bounds__(256, 2) void k_zr(const float* __restrict__ z,
                                               const float* __restrict__ rfm,
                                               const float* __restrict__ sqz,
                                               const float* __restrict__ sqr,
                                               const float* __restrict__ curv,
                                               double* __restrict__ pS,
                                               float* __restrict__ pM) {
  __shared__ struct { ushort Ah[4096], Al[4096], Bh[4096], Bl[4096]; } s;
  const int t = blockIdx.x;
  int ib = 0, base = 0;
  while (base + (32 - ib) <= t) { base += 32 - ib; ++ib; }
  const int jb = ib + (t - base);
  const int i0 = ib * 128, j0 = jb * 128;
  const int tid = threadIdx.x;
  const int lane = tid & 63, wv = tid >> 6;
  const int wr = wv >> 1, wc = wv & 1;
  const int fr = lane & 15, fg = lane >> 4;

  f32x4 zacc[4][4], racc[4][4];
  const f32x4 zv = {0.f, 0.f, 0.f, 0.f};
#pragma unroll
  for (int m = 0; m < 4; ++m)
#pragma unroll
    for (int n = 0; n < 4; ++n) { zacc[m][n] = zv; racc[m][n] = zv; }

#pragma unroll
  for (int mat = 0; mat < 2; ++mat) {
    const float* P = mat ? rfm : z;
    for (int kc = 0; kc < DZ; kc += 32) {
      __syncthreads();
#pragma unroll
      for (int l = 0; l < 4; ++l) {
        int idx = tid + l * 256;
        int row = idx >> 3, c4 = idx & 7;
        int off = (row << 6) + (c4 << 3);
        off ^= (row & 7) << 4;
        float4 va = *(const float4*)&P[(size_t)(i0 + row) * DZ + kc + c4 * 4];
        float4 vb = *(const float4*)&P[(size_t)(j0 + row) * DZ + kc + c4 * 4];
        float av[4] = {va.x, va.y, va.z, va.w};
        float bv[4] = {vb.x, vb.y, vb.z, vb.w};
        ushort ah4[4], al4[4], bh4[4], bl4[4];
#pragma unroll
        for (int e = 0; e < 4; ++e) {
          ah4[e] = f2bf(av[e]); al4[e] = f2bf(av[e] - bf2f(ah4[e]));
          bh4[e] = f2bf(bv[e]); bl4[e] = f2bf(bv[e] - bf2f(bh4[e]));
        }
        uint2 p;
        p.x = (unsigned)ah4[0] | ((unsigned)ah4[1] << 16);
        p.y = (unsigned)ah4[2] | ((unsigned)ah4[3] << 16);
        *(uint2*)((char*)s.Ah + off) = p;
        p.x = (unsigned)al4[0] | ((unsigned)al4[1] << 16);
        p.y = (unsigned)al4[2] | ((unsigned)al4[3] << 16);
        *(uint2*)((char*)s.Al + off) = p;
        p.x = (unsigned)bh4[0] | ((unsigned)bh4[1] << 16);
        p.y = (unsigned)bh4[2] | ((unsigned)bh4[3] << 16);
        *(uint2*)((char*)s.Bh + off) = p;
        p.x = (unsigned)bl4[0] | ((unsigned)bl4[1] << 16);
        p.y = (unsigned)bl4[2] | ((unsigned)bl4[3] << 16);
        *(uint2*)((char*)s.Bl + off) = p;
      }
      __syncthreads();
      short8v fah[4], fal[4];
#pragma unroll
      for (int m = 0; m < 4; ++m) {
        int r = wr * 64 + m * 16 + fr;
        fah[m] = frag_ld(s.Ah, r, fg);
        fal[m] = frag_ld(s.Al, r, fg);
      }
#pragma unroll
      for (int n = 0; n < 4; ++n) {
        int r = wc * 64 + n * 16 + fr;
        short8v fbh = frag_ld(s.Bh, r, fg);
        short8v fbl = frag_ld(s.Bl, r, fg);
#pragma unroll
        for (int m = 0; m < 4; ++m) {
          if (mat == 0) {
            zacc[m][n] = MFMA16(fah[m], fbh, zacc[m][n]);
            zacc[m][n] = MFMA16(fah[m], fbl, zacc[m][n]);
            zacc[m][n] = MFMA16(fal[m], fbh, zacc[m][n]);
          } else {
            racc[m][n] = MFMA16(fah[m], fbh, racc[m][n]);
            racc[m][n] = MFMA16(fah[m], fbl, racc[m][n]);
            racc[m][n] = MFMA16(fal[m], fbh, racc[m][n]);
          }
        }
      }
    }
  }

  double s1 = 0, s2 = 0, s3 = 0;
  float mz = 0.f, mr = 0.f;
#pragma unroll
  for (int m = 0; m < 4; ++m)
#pragma unroll
    for (int n = 0; n < 4; ++n)
#pragma unroll
      for (int r = 0; r < 4; ++r) {
        int gi = i0 + wr * 64 + m * 16 + fg * 4 + r;
        int gj = j0 + wc * 64 + n * 16 + fr;
        if (gj > gi) {
          float z2 = fmaxf(sqz[gi] + sqz[gj] - 2.f * zacc[m][n][r], 0.f);
          float r2 = fmaxf(sqr[gi] + sqr[gj] - 2.f * racc[m][n][r], 0.f);
          float w = fmaxf(1.f - fmaxf(curv[gi], curv[gj]), 0.1f);
          s1 += (double)(w * z2);
          s3 += (double)(w * r2);
          s2 += (double)(w * sqrtf(z2 * r2));
          mz = fmaxf(mz, z2);
          mr = fmaxf(mr, r2);
        }
      }
#pragma unroll
  for (int m = 32; m; m >>= 1) {
    s1 += __shfl_xor(s1, m);
    s2 += __shfl_xor(s2, m);
    s3 += __shfl_xor(s3, m);
    mz = fmaxf(mz, __shfl_xor(mz, m));
    mr = fmaxf(mr, __shfl_xor(mr, m));
  }
  __shared__ double rd[4][3];
  __shared__ float rf2[4][2];
  int w = tid >> 6;
  if ((tid & 63) == 0) { rd[w][0] = s1; rd[w][1] = s2; rd[w][2] = s3; rf2[w][0] = mz; rf2[w][1] = mr; }
  __syncthreads();
  if (tid == 0) {
    double a = 0, b = 0, c = 0; float d = 0.f, e = 0.f;
    for (int i = 0; i < 4; ++i) {
      a += rd[i][0]; b += rd[i][1]; c += rd[i][2];
      d = fmaxf(d, rf2[i][0]); e = fmaxf(e, rf2[i][1]);
    }
    pS[(size_t)t * 3 + 0] = a; pS[(size_t)t * 3 + 1] = b; pS[(size_t)t * 3 + 2] = c;
    pM[(size_t)t * 2 + 0] = d; pM[(size_t)t * 2 + 1] = e;
  }
}

// ---------------- final combine ----------------
__global__ __launch_bounds__(256) void k_final(const double* __restrict__ pS,
                                               const float* __restrict__ pM,
                                               int nb, float* __restrict__ out) {
  int tid = threadIdx.x;
  double s1 = 0, s2 = 0, s3 = 0; float mz = 0.f, mr = 0.f;
  for (int i = tid; i < nb; i += 256) {
    s1 += pS[(size_t)i * 3 + 0]; s2 += pS[(size_t)i * 3 + 1]; s3 += pS[(size_t)i * 3 + 2];
    mz = fmaxf(mz, pM[(size_t)i * 2 + 0]); mr = fmaxf(mr, pM[(size_t)i * 2 + 1]);
  }
#pragma unroll
  for (int m = 32; m; m >>= 1) {
    s1 += __shfl_xor(s1, m); s2 += __shfl_xor(s2, m); s3 += __shfl_xor(s3, m);
    mz = fmaxf(mz, __shfl_xor(mz, m)); mr = fmaxf(mr, __shfl_xor(mr, m));
  }
  __shared__ double rd[4][3];
  __shared__ float rf2[4][2];
  int w = tid >> 6;
  if ((tid & 63) == 0) { rd[w][0] = s1; rd[w][1] = s2; rd[w][2] = s3; rf2[w][0] = mz; rf2[w][1] = mr; }
  __syncthreads();
  if (tid == 0) {
    double a = 0, b = 0, c = 0; float d = 0.f, e = 0.f;
    for (int i = 0; i < 4; ++i) {
      a += rd[i][0]; b += rd[i][1]; c += rd[i][2];
      d = fmaxf(d, rf2[i][0]); e = fmaxf(e, rf2[i][1]);
    }
    double zm = sqrt((double)d) + 1e-8;
    double rm = sqrt((double)e) + 1e-8;
    double total = a / (zm * zm) - 2.0 * b / (zm * rm) + c / (rm * rm);
    double npairs = (double)NB * (double)(NB - 1) / 2.0;
    out[0] = (float)(total / npairs);
  }
}

extern "C" void kernel_launch(void* const* d_in, const int* in_sizes, int n_in,
                              void* d_out, int out_size, void* d_ws, size_t ws_size,
                              hipStream_t stream) {
  const float* z = (const float*)d_in[0];
  const float* rfm = (const float*)d_in[1];
  const float* x = (const float*)d_in[2];
  float* out = (float*)d_out;
  char* w = (char*)d_ws;

  float*  sqx    = (float*)(w + 0);         // 16 KB
  float*  sqz    = (float*)(w + 16384);
  float*  sqr    = (float*)(w + 32768);
  float*  curv   = (float*)(w + 49152);
  int*    knn    = (int*)(w + 65536);       // 160 KB
  float*  cand_d = (float*)(w + 229376);    // 2.62 MB
  int*    cand_i = (int*)(w + 2850816);     // 2.62 MB
  float*  G      = (float*)(w + 5472256);   // 900 KB
  double* pS     = (double*)(w + 6373376);  // 12.7 KB
  float*  pM     = (float*)(w + 6386048);   // 4.2 KB

  const size_t pre_need = (size_t)24 * 1024 * 1024;
  const bool pre = ws_size >= pre_need;
  ushort* xh = (ushort*)(w + (size_t)8 * 1024 * 1024);   // 8 MB
  ushort* xl = (ushort*)(w + (size_t)16 * 1024 * 1024);  // 8 MB

  k_rowsq<<<NB, 256, 0, stream>>>(x, sqx, DX);
  k_rowsq<<<NB, 256, 0, stream>>>(z, sqz, DZ);
  k_rowsq<<<NB, 256, 0, stream>>>(rfm, sqr, DZ);
  if (pre) {
    k_split<<<NB * DX / 4 / 256, 256, 0, stream>>>(x, xh, xl);
    k_knn<1><<<dim3(STR, NB / 128), 256, 0, stream>>>(x, xh, xl, sqx, cand_d, cand_i);
  } else {
    k_knn<0><<<dim3(STR, NB / 128), 256, 0, stream>>>(x, xh, xl, sqx, cand_d, cand_i);
  }
  k_merge<<<NB / 64, 64, 0, stream>>>(cand_d, cand_i, knn);
  k_gram<<<NB, 64, 0, stream>>>(x, knn, G);
  k_jacobi<<<NB / 64, 64, 0, stream>>>(G, curv);
  k_zr<<<528, 256, 0, stream>>>(z, rfm, sqz, sqr, curv, pS, pM);
  k_final<<<1, 256, 0, stream>>>(pS, pM, 528, out);
}

// Round 3
// 407.105 us; speedup vs baseline: 3.4852x; 1.8551x over previous
//
#include <hip/hip_runtime.h>
#include <math.h>

#define NB 4096
#define DX 1024
#define DZ 128
#define KNN 10
#define STR 16
#define SLEN (NB / STR) /* 256 */

typedef short short8v __attribute__((ext_vector_type(8)));
typedef float f32x4 __attribute__((ext_vector_type(4)));

#define MFMA16(a, b, c) __builtin_amdgcn_mfma_f32_16x16x32_bf16((a), (b), (c), 0, 0, 0)

__device__ __forceinline__ ushort f2bf(float f) {
  unsigned u = __float_as_uint(f);
  u += 0x7FFFu + ((u >> 16) & 1u);
  return (ushort)(u >> 16);
}
__device__ __forceinline__ float bf2f(ushort h) {
  return __uint_as_float(((unsigned)h) << 16);
}

// swizzled LDS fragment load: 8 contiguous bf16 at [row][fg*8]
__device__ __forceinline__ short8v frag_ld(const ushort* base, int row, int fg) {
  int off = (row << 6) + (fg << 4);
  off ^= (row & 7) << 4;
  return *(const short8v*)((const char*)base + off);
}

// ---------------- row sum of squares ----------------
__global__ __launch_bounds__(256) void k_rowsq(const float* __restrict__ a,
                                               float* __restrict__ out, int D) {
  int row = blockIdx.x;
  const float* p = a + (size_t)row * D;
  float s = 0.f;
  for (int d = threadIdx.x; d < D; d += 256) { float v = p[d]; s = fmaf(v, v, s); }
#pragma unroll
  for (int m = 32; m; m >>= 1) s += __shfl_xor(s, m);
  __shared__ float red[4];
  int w = threadIdx.x >> 6;
  if ((threadIdx.x & 63) == 0) red[w] = s;
  __syncthreads();
  if (threadIdx.x == 0) out[row] = red[0] + red[1] + red[2] + red[3];
}

// ---------------- split x into bf16 hi/lo ----------------
__global__ __launch_bounds__(256) void k_split(const float* __restrict__ a,
                                               ushort* __restrict__ hi,
                                               ushort* __restrict__ lo) {
  int idx = blockIdx.x * 256 + threadIdx.x;
  float4 v = ((const float4*)a)[idx];
  float vv[4] = {v.x, v.y, v.z, v.w};
  ushort h[4], l[4];
#pragma unroll
  for (int e = 0; e < 4; ++e) {
    h[e] = f2bf(vv[e]);
    l[e] = f2bf(vv[e] - bf2f(h[e]));
  }
  ushort4 hv; hv.x = h[0]; hv.y = h[1]; hv.z = h[2]; hv.w = h[3];
  ushort4 lv; lv.x = l[0]; lv.y = l[1]; lv.z = l[2]; lv.w = l[3];
  ((ushort4*)hi)[idx] = hv;
  ((ushort4*)lo)[idx] = lv;
}

// ---------------- kNN via MFMA: 128x128 tiles, strip top-10 ----------------
struct SmemKNN {
  union {
    struct { ushort Ah[4096], Al[4096], Bh[4096], Bl[4096]; } s;  // 32 KB
    float D[128 * 129];                                           // 66 KB
  } u;
  float td[128][KNN];
  int   ti[128][KNN];
};

template<int PRE>
__global__ __launch_bounds__(256, 2) void k_knn(const float* __restrict__ x,
                                                const ushort* __restrict__ xh,
                                                const ushort* __restrict__ xl,
                                                const float* __restrict__ sqx,
                                                float* __restrict__ cand_d,
                                                int* __restrict__ cand_i) {
  __shared__ SmemKNN sm;
  const int strip = blockIdx.x;
  const int i0 = blockIdx.y * 128;
  const int tid = threadIdx.x;
  const int lane = tid & 63, wv = tid >> 6;
  const int wr = wv >> 1, wc = wv & 1;
  const int fr = lane & 15, fg = lane >> 4;

  for (int idx = tid; idx < 128 * KNN; idx += 256) {
    ((float*)sm.td)[idx] = 3.0e38f;
    ((int*)sm.ti)[idx] = 0;
  }

  for (int jt = 0; jt < SLEN / 128; ++jt) {
    const int j0 = strip * SLEN + jt * 128;
    f32x4 acc[4][4];
    const f32x4 zv = {0.f, 0.f, 0.f, 0.f};
#pragma unroll
    for (int m = 0; m < 4; ++m)
#pragma unroll
      for (int n = 0; n < 4; ++n) acc[m][n] = zv;

    for (int kc = 0; kc < DX; kc += 32) {
      __syncthreads();
      if (PRE) {
#pragma unroll
        for (int l = 0; l < 2; ++l) {
          int idx = tid + l * 256;            // 0..511
          int row = idx >> 2, c8 = idx & 3;   // 8 bf16 per c8
          int off = (row << 6) + (c8 << 4);
          off ^= (row & 7) << 4;
          size_t ga = (size_t)(i0 + row) * DX + kc + c8 * 8;
          size_t gb = (size_t)(j0 + row) * DX + kc + c8 * 8;
          *(uint4*)((char*)sm.u.s.Ah + off) = *(const uint4*)(xh + ga);
          *(uint4*)((char*)sm.u.s.Al + off) = *(const uint4*)(xl + ga);
          *(uint4*)((char*)sm.u.s.Bh + off) = *(const uint4*)(xh + gb);
          *(uint4*)((char*)sm.u.s.Bl + off) = *(const uint4*)(xl + gb);
        }
      } else {
#pragma unroll
        for (int l = 0; l < 4; ++l) {
          int idx = tid + l * 256;            // 0..1023
          int row = idx >> 3, c4 = idx & 7;
          int off = (row << 6) + (c4 << 3);
          off ^= (row & 7) << 4;
          float4 va = *(const float4*)&x[(size_t)(i0 + row) * DX + kc + c4 * 4];
          float4 vb = *(const float4*)&x[(size_t)(j0 + row) * DX + kc + c4 * 4];
          float av[4] = {va.x, va.y, va.z, va.w};
          float bv[4] = {vb.x, vb.y, vb.z, vb.w};
          ushort ah4[4], al4[4], bh4[4], bl4[4];
#pragma unroll
          for (int e = 0; e < 4; ++e) {
            ah4[e] = f2bf(av[e]); al4[e] = f2bf(av[e] - bf2f(ah4[e]));
            bh4[e] = f2bf(bv[e]); bl4[e] = f2bf(bv[e] - bf2f(bh4[e]));
          }
          uint2 p;
          p.x = (unsigned)ah4[0] | ((unsigned)ah4[1] << 16);
          p.y = (unsigned)ah4[2] | ((unsigned)ah4[3] << 16);
          *(uint2*)((char*)sm.u.s.Ah + off) = p;
          p.x = (unsigned)al4[0] | ((unsigned)al4[1] << 16);
          p.y = (unsigned)al4[2] | ((unsigned)al4[3] << 16);
          *(uint2*)((char*)sm.u.s.Al + off) = p;
          p.x = (unsigned)bh4[0] | ((unsigned)bh4[1] << 16);
          p.y = (unsigned)bh4[2] | ((unsigned)bh4[3] << 16);
          *(uint2*)((char*)sm.u.s.Bh + off) = p;
          p.x = (unsigned)bl4[0] | ((unsigned)bl4[1] << 16);
          p.y = (unsigned)bl4[2] | ((unsigned)bl4[3] << 16);
          *(uint2*)((char*)sm.u.s.Bl + off) = p;
        }
      }
      __syncthreads();
      short8v fah[4], fal[4];
#pragma unroll
      for (int m = 0; m < 4; ++m) {
        int r = wr * 64 + m * 16 + fr;
        fah[m] = frag_ld(sm.u.s.Ah, r, fg);
        fal[m] = frag_ld(sm.u.s.Al, r, fg);
      }
#pragma unroll
      for (int n = 0; n < 4; ++n) {
        int r = wc * 64 + n * 16 + fr;
        short8v fbh = frag_ld(sm.u.s.Bh, r, fg);
        short8v fbl = frag_ld(sm.u.s.Bl, r, fg);
#pragma unroll
        for (int m = 0; m < 4; ++m) {
          acc[m][n] = MFMA16(fah[m], fbh, acc[m][n]);
          acc[m][n] = MFMA16(fah[m], fbl, acc[m][n]);
          acc[m][n] = MFMA16(fal[m], fbh, acc[m][n]);
        }
      }
    }
    __syncthreads();
#pragma unroll
    for (int m = 0; m < 4; ++m)
#pragma unroll
      for (int n = 0; n < 4; ++n)
#pragma unroll
        for (int r = 0; r < 4; ++r) {
          int rl = wr * 64 + m * 16 + fg * 4 + r;
          int cl = wc * 64 + n * 16 + fr;
          int gi = i0 + rl, gj = j0 + cl;
          float v = sqx[gi] + sqx[gj] - 2.f * acc[m][n][r];
          sm.u.D[rl * 129 + cl] = (gi == gj) ? 3.0e38f : v;
        }
    __syncthreads();
    if (tid < 128) {
      for (int c = 0; c < 128; ++c) {
        float v = sm.u.D[tid * 129 + c];
        if (v < sm.td[tid][KNN - 1]) {
          int p = KNN - 1;
          while (p > 0 && sm.td[tid][p - 1] > v) {
            sm.td[tid][p] = sm.td[tid][p - 1];
            sm.ti[tid][p] = sm.ti[tid][p - 1];
            --p;
          }
          sm.td[tid][p] = v;
          sm.ti[tid][p] = j0 + c;
        }
      }
    }
  }
  __syncthreads();
  if (tid < 128) {
    int row = i0 + tid;
#pragma unroll
    for (int l = 0; l < KNN; ++l) {
      cand_d[((size_t)row * STR + strip) * KNN + l] = sm.td[tid][l];
      cand_i[((size_t)row * STR + strip) * KNN + l] = sm.ti[tid][l];
    }
  }
}

// ---------------- merge strip candidates -> global top-10 ----------------
__global__ __launch_bounds__(64) void k_merge(const float* __restrict__ cand_d,
                                              const int* __restrict__ cand_i,
                                              int* __restrict__ knn) {
  __shared__ float td[64][KNN];
  __shared__ int   ti[64][KNN];
  int t = threadIdx.x;
  int row = blockIdx.x * 64 + t;
  for (int l = 0; l < KNN; ++l) { td[t][l] = 3.0e38f; ti[t][l] = 0; }
  for (int s = 0; s < STR; ++s)
    for (int l = 0; l < KNN; ++l) {
      float v = cand_d[((size_t)row * STR + s) * KNN + l];
      int j = cand_i[((size_t)row * STR + s) * KNN + l];
      if (v < td[t][KNN - 1]) {
        int p = KNN - 1;
        while (p > 0 && td[t][p - 1] > v) {
          td[t][p] = td[t][p - 1]; ti[t][p] = ti[t][p - 1]; --p;
        }
        td[t][p] = v; ti[t][p] = j;
      }
    }
  for (int l = 0; l < KNN; ++l) knn[row * KNN + l] = ti[t][l];
}

// ---------------- Gram matrix of centered neighbors (one wave / point) ----
__global__ __launch_bounds__(64) void k_gram(const float* __restrict__ x,
                                             const int* __restrict__ knn,
                                             float* __restrict__ G) {
  const int pt = blockIdx.x;
  const int lane = threadIdx.x;
  int nb[KNN];
#pragma unroll
  for (int a = 0; a < KNN; ++a) nb[a] = knn[pt * KNN + a];
  float P[55];
  float U[KNN];
  float q = 0.f;
#pragma unroll
  for (int c = 0; c < 55; ++c) P[c] = 0.f;
#pragma unroll
  for (int a = 0; a < KNN; ++a) U[a] = 0.f;
  for (int d = lane; d < DX; d += 64) {
    float n[KNN];
#pragma unroll
    for (int a = 0; a < KNN; ++a) n[a] = x[(size_t)nb[a] * DX + d];
    float m = 0.f;
#pragma unroll
    for (int a = 0; a < KNN; ++a) m += n[a];
    m *= 0.1f;
    q = fmaf(m, m, q);
#pragma unroll
    for (int a = 0; a < KNN; ++a) U[a] = fmaf(n[a], m, U[a]);
    int c = 0;
#pragma unroll
    for (int a = 0; a < KNN; ++a)
#pragma unroll
      for (int b = a; b < KNN; ++b) { P[c] = fmaf(n[a], n[b], P[c]); ++c; }
  }
#pragma unroll
  for (int c = 0; c < 55; ++c)
#pragma unroll
    for (int m2 = 32; m2; m2 >>= 1) P[c] += __shfl_xor(P[c], m2);
#pragma unroll
  for (int a = 0; a < KNN; ++a)
#pragma unroll
    for (int m2 = 32; m2; m2 >>= 1) U[a] += __shfl_xor(U[a], m2);
#pragma unroll
  for (int m2 = 32; m2; m2 >>= 1) q += __shfl_xor(q, m2);
  if (lane == 0) {
    int c = 0;
    for (int a = 0; a < KNN; ++a)
      for (int b = a; b < KNN; ++b) { G[(size_t)pt * 55 + c] = P[c] - U[a] - U[b] + q; ++c; }
  }
}

// ---------------- Jacobi eigenvalues of 10x10 in registers ---------------
// Symmetric storage: IJ(a,b) for a<=b; row a starts at 10a - a(a-1)/2.
__device__ __forceinline__ constexpr int IJ(int a, int b) {
  return (a <= b) ? (10 * a - (a * (a - 1)) / 2 + (b - a))
                  : (10 * b - (b * (b - 1)) / 2 + (a - b));
}

#define NSWEEP 6
__global__ __launch_bounds__(64) void k_jacobi(const float* __restrict__ G,
                                               float* __restrict__ curv) {
  const int pt = blockIdx.x * 64 + threadIdx.x;
  float M[55];
#pragma unroll
  for (int c = 0; c < 55; ++c) M[c] = G[(size_t)pt * 55 + c];

#pragma unroll
  for (int sweep = 0; sweep < NSWEEP; ++sweep) {
#pragma unroll
    for (int p = 0; p < KNN - 1; ++p) {
#pragma unroll
      for (int q = p + 1; q < KNN; ++q) {
        float apq = M[IJ(p, q)];
        float app = M[IJ(p, p)], aqq = M[IJ(q, q)];
        float theta = (aqq - app) / (2.f * apq);
        float t = 1.f / (fabsf(theta) + sqrtf(fmaf(theta, theta, 1.f)));
        t = (theta < 0.f) ? -t : t;
        t = (apq == 0.f) ? 0.f : t;   // guards 0/0 NaN path, branchless
        float cc = 1.f / sqrtf(fmaf(t, t, 1.f));
        float ss = t * cc;
#pragma unroll
        for (int r = 0; r < KNN; ++r) {
          if (r == p || r == q) continue;
          float vrp = M[IJ(r, p)];
          float vrq = M[IJ(r, q)];
          M[IJ(r, p)] = cc * vrp - ss * vrq;
          M[IJ(r, q)] = ss * vrp + cc * vrq;
        }
        M[IJ(p, p)] = app - t * apq;
        M[IJ(q, q)] = aqq + t * apq;
        M[IJ(p, q)] = 0.f;
      }
    }
  }

  float lmax = 0.f, ssum = 0.f;
#pragma unroll
  for (int a = 0; a < KNN; ++a) {
    float l = fmaxf(M[IJ(a, a)], 0.f);
    lmax = fmaxf(lmax, l);
    ssum += sqrtf(l);
  }
  curv[pt] = 1.f - sqrtf(lmax) / (ssum + 1e-8f);
}

// ---------------- fused z/ref upper-triangle pass (MFMA) ----------------
__global__ __launch_bounds__(256, 2) void k_zr(const float* __restrict__ z,
                                               const float* __restrict__ rfm,
                                               const float* __restrict__ sqz,
                                               const float* __restrict__ sqr,
                                               const float* __restrict__ curv,
                                               double* __restrict__ pS,
                                               float* __restrict__ pM) {
  __shared__ struct { ushort Ah[4096], Al[4096], Bh[4096], Bl[4096]; } s;
  const int t = blockIdx.x;
  int ib = 0, base = 0;
  while (base + (32 - ib) <= t) { base += 32 - ib; ++ib; }
  const int jb = ib + (t - base);
  const int i0 = ib * 128, j0 = jb * 128;
  const int tid = threadIdx.x;
  const int lane = tid & 63, wv = tid >> 6;
  const int wr = wv >> 1, wc = wv & 1;
  const int fr = lane & 15, fg = lane >> 4;

  f32x4 zacc[4][4], racc[4][4];
  const f32x4 zv = {0.f, 0.f, 0.f, 0.f};
#pragma unroll
  for (int m = 0; m < 4; ++m)
#pragma unroll
    for (int n = 0; n < 4; ++n) { zacc[m][n] = zv; racc[m][n] = zv; }

#pragma unroll
  for (int mat = 0; mat < 2; ++mat) {
    const float* P = mat ? rfm : z;
    for (int kc = 0; kc < DZ; kc += 32) {
      __syncthreads();
#pragma unroll
      for (int l = 0; l < 4; ++l) {
        int idx = tid + l * 256;
        int row = idx >> 3, c4 = idx & 7;
        int off = (row << 6) + (c4 << 3);
        off ^= (row & 7) << 4;
        float4 va = *(const float4*)&P[(size_t)(i0 + row) * DZ + kc + c4 * 4];
        float4 vb = *(const float4*)&P[(size_t)(j0 + row) * DZ + kc + c4 * 4];
        float av[4] = {va.x, va.y, va.z, va.w};
        float bv[4] = {vb.x, vb.y, vb.z, vb.w};
        ushort ah4[4], al4[4], bh4[4], bl4[4];
#pragma unroll
        for (int e = 0; e < 4; ++e) {
          ah4[e] = f2bf(av[e]); al4[e] = f2bf(av[e] - bf2f(ah4[e]));
          bh4[e] = f2bf(bv[e]); bl4[e] = f2bf(bv[e] - bf2f(bh4[e]));
        }
        uint2 p;
        p.x = (unsigned)ah4[0] | ((unsigned)ah4[1] << 16);
        p.y = (unsigned)ah4[2] | ((unsigned)ah4[3] << 16);
        *(uint2*)((char*)s.Ah + off) = p;
        p.x = (unsigned)al4[0] | ((unsigned)al4[1] << 16);
        p.y = (unsigned)al4[2] | ((unsigned)al4[3] << 16);
        *(uint2*)((char*)s.Al + off) = p;
        p.x = (unsigned)bh4[0] | ((unsigned)bh4[1] << 16);
        p.y = (unsigned)bh4[2] | ((unsigned)bh4[3] << 16);
        *(uint2*)((char*)s.Bh + off) = p;
        p.x = (unsigned)bl4[0] | ((unsigned)bl4[1] << 16);
        p.y = (unsigned)bl4[2] | ((unsigned)bl4[3] << 16);
        *(uint2*)((char*)s.Bl + off) = p;
      }
      __syncthreads();
      short8v fah[4], fal[4];
#pragma unroll
      for (int m = 0; m < 4; ++m) {
        int r = wr * 64 + m * 16 + fr;
        fah[m] = frag_ld(s.Ah, r, fg);
        fal[m] = frag_ld(s.Al, r, fg);
      }
#pragma unroll
      for (int n = 0; n < 4; ++n) {
        int r = wc * 64 + n * 16 + fr;
        short8v fbh = frag_ld(s.Bh, r, fg);
        short8v fbl = frag_ld(s.Bl, r, fg);
#pragma unroll
        for (int m = 0; m < 4; ++m) {
          if (mat == 0) {
            zacc[m][n] = MFMA16(fah[m], fbh, zacc[m][n]);
            zacc[m][n] = MFMA16(fah[m], fbl, zacc[m][n]);
            zacc[m][n] = MFMA16(fal[m], fbh, zacc[m][n]);
          } else {
            racc[m][n] = MFMA16(fah[m], fbh, racc[m][n]);
            racc[m][n] = MFMA16(fah[m], fbl, racc[m][n]);
            racc[m][n] = MFMA16(fal[m], fbh, racc[m][n]);
          }
        }
      }
    }
  }

  double s1 = 0, s2 = 0, s3 = 0;
  float mz = 0.f, mr = 0.f;
#pragma unroll
  for (int m = 0; m < 4; ++m)
#pragma unroll
    for (int n = 0; n < 4; ++n)
#pragma unroll
      for (int r = 0; r < 4; ++r) {
        int gi = i0 + wr * 64 + m * 16 + fg * 4 + r;
        int gj = j0 + wc * 64 + n * 16 + fr;
        if (gj > gi) {
          float z2 = fmaxf(sqz[gi] + sqz[gj] - 2.f * zacc[m][n][r], 0.f);
          float r2 = fmaxf(sqr[gi] + sqr[gj] - 2.f * racc[m][n][r], 0.f);
          float w = fmaxf(1.f - fmaxf(curv[gi], curv[gj]), 0.1f);
          s1 += (double)(w * z2);
          s3 += (double)(w * r2);
          s2 += (double)(w * sqrtf(z2 * r2));
          mz = fmaxf(mz, z2);
          mr = fmaxf(mr, r2);
        }
      }
#pragma unroll
  for (int m = 32; m; m >>= 1) {
    s1 += __shfl_xor(s1, m);
    s2 += __shfl_xor(s2, m);
    s3 += __shfl_xor(s3, m);
    mz = fmaxf(mz, __shfl_xor(mz, m));
    mr = fmaxf(mr, __shfl_xor(mr, m));
  }
  __shared__ double rd[4][3];
  __shared__ float rf2[4][2];
  int w = tid >> 6;
  if ((tid & 63) == 0) { rd[w][0] = s1; rd[w][1] = s2; rd[w][2] = s3; rf2[w][0] = mz; rf2[w][1] = mr; }
  __syncthreads();
  if (tid == 0) {
    double a = 0, b = 0, c = 0; float d = 0.f, e = 0.f;
    for (int i = 0; i < 4; ++i) {
      a += rd[i][0]; b += rd[i][1]; c += rd[i][2];
      d = fmaxf(d, rf2[i][0]); e = fmaxf(e, rf2[i][1]);
    }
    pS[(size_t)t * 3 + 0] = a; pS[(size_t)t * 3 + 1] = b; pS[(size_t)t * 3 + 2] = c;
    pM[(size_t)t * 2 + 0] = d; pM[(size_t)t * 2 + 1] = e;
  }
}

// ---------------- final combine ----------------
__global__ __launch_bounds__(256) void k_final(const double* __restrict__ pS,
                                               const float* __restrict__ pM,
                                               int nb, float* __restrict__ out) {
  int tid = threadIdx.x;
  double s1 = 0, s2 = 0, s3 = 0; float mz = 0.f, mr = 0.f;
  for (int i = tid; i < nb; i += 256) {
    s1 += pS[(size_t)i * 3 + 0]; s2 += pS[(size_t)i * 3 + 1]; s3 += pS[(size_t)i * 3 + 2];
    mz = fmaxf(mz, pM[(size_t)i * 2 + 0]); mr = fmaxf(mr, pM[(size_t)i * 2 + 1]);
  }
#pragma unroll
  for (int m = 32; m; m >>= 1) {
    s1 += __shfl_xor(s1, m); s2 += __shfl_xor(s2, m); s3 += __shfl_xor(s3, m);
    mz = fmaxf(mz, __shfl_xor(mz, m)); mr = fmaxf(mr, __shfl_xor(mr, m));
  }
  __shared__ double rd[4][3];
  __shared__ float rf2[4][2];
  int w = tid >> 6;
  if ((tid & 63) == 0) { rd[w][0] = s1; rd[w][1] = s2; rd[w][2] = s3; rf2[w][0] = mz; rf2[w][1] = mr; }
  __syncthreads();
  if (tid == 0) {
    double a = 0, b = 0, c = 0; float d = 0.f, e = 0.f;
    for (int i = 0; i < 4; ++i) {
      a += rd[i][0]; b += rd[i][1]; c += rd[i][2];
      d = fmaxf(d, rf2[i][0]); e = fmaxf(e, rf2[i][1]);
    }
    double zm = sqrt((double)d) + 1e-8;
    double rm = sqrt((double)e) + 1e-8;
    double total = a / (zm * zm) - 2.0 * b / (zm * rm) + c / (rm * rm);
    double npairs = (double)NB * (double)(NB - 1) / 2.0;
    out[0] = (float)(total / npairs);
  }
}

extern "C" void kernel_launch(void* const* d_in, const int* in_sizes, int n_in,
                              void* d_out, int out_size, void* d_ws, size_t ws_size,
                              hipStream_t stream) {
  const float* z = (const float*)d_in[0];
  const float* rfm = (const float*)d_in[1];
  const float* x = (const float*)d_in[2];
  float* out = (float*)d_out;
  char* w = (char*)d_ws;

  float*  sqx    = (float*)(w + 0);         // 16 KB
  float*  sqz    = (float*)(w + 16384);
  float*  sqr    = (float*)(w + 32768);
  float*  curv   = (float*)(w + 49152);
  int*    knn    = (int*)(w + 65536);       // 160 KB
  float*  cand_d = (float*)(w + 229376);    // 2.62 MB
  int*    cand_i = (int*)(w + 2850816);     // 2.62 MB
  float*  G      = (float*)(w + 5472256);   // 900 KB
  double* pS     = (double*)(w + 6373376);  // 12.7 KB
  float*  pM     = (float*)(w + 6386048);   // 4.2 KB

  const size_t pre_need = (size_t)24 * 1024 * 1024;
  const bool pre = ws_size >= pre_need;
  ushort* xh = (ushort*)(w + (size_t)8 * 1024 * 1024);   // 8 MB
  ushort* xl = (ushort*)(w + (size_t)16 * 1024 * 1024);  // 8 MB

  k_rowsq<<<NB, 256, 0, stream>>>(x, sqx, DX);
  k_rowsq<<<NB, 256, 0, stream>>>(z, sqz, DZ);
  k_rowsq<<<NB, 256, 0, stream>>>(rfm, sqr, DZ);
  if (pre) {
    k_split<<<NB * DX / 4 / 256, 256, 0, stream>>>(x, xh, xl);
    k_knn<1><<<dim3(STR, NB / 128), 256, 0, stream>>>(x, xh, xl, sqx, cand_d, cand_i);
  } else {
    k_knn<0><<<dim3(STR, NB / 128), 256, 0, stream>>>(x, xh, xl, sqx, cand_d, cand_i);
  }
  k_merge<<<NB / 64, 64, 0, stream>>>(cand_d, cand_i, knn);
  k_gram<<<NB, 64, 0, stream>>>(x, knn, G);
  k_jacobi<<<NB / 64, 64, 0, stream>>>(G, curv);
  k_zr<<<528, 256, 0, stream>>>(z, rfm, sqz, sqr, curv, pS, pM);
  k_final<<<1, 256, 0, stream>>>(pS, pM, 528, out);
}

// Round 4
// 383.947 us; speedup vs baseline: 3.6955x; 1.0603x over previous
//
#include <hip/hip_runtime.h>
#include <math.h>

#define NB 4096
#define DX 1024
#define DZ 128
#define KNN 10
#define STR 16
#define SLEN (NB / STR) /* 256 */
#define NLIST (STR * 2)  /* 32 candidate lists per row */

typedef short short8v __attribute__((ext_vector_type(8)));
typedef float f32x4 __attribute__((ext_vector_type(4)));

#define MFMA16(a, b, c) __builtin_amdgcn_mfma_f32_16x16x32_bf16((a), (b), (c), 0, 0, 0)

__device__ __forceinline__ ushort f2bf(float f) {
  unsigned u = __float_as_uint(f);
  u += 0x7FFFu + ((u >> 16) & 1u);
  return (ushort)(u >> 16);
}
__device__ __forceinline__ float bf2f(ushort h) {
  return __uint_as_float(((unsigned)h) << 16);
}

// swizzled LDS fragment load: 8 contiguous bf16 at [row][fg*8]
__device__ __forceinline__ short8v frag_ld(const ushort* base, int row, int fg) {
  int off = (row << 6) + (fg << 4);
  off ^= (row & 7) << 4;
  return *(const short8v*)((const char*)base + off);
}

// branchless register top-10 insert (all indices static after unroll)
#define INSERT10(td, ti, v, idx)                         \
  do {                                                   \
    if ((v) < td[KNN - 1]) {                             \
      _Pragma("unroll")                                  \
      for (int k_ = KNN - 1; k_ >= 1; --k_) {            \
        bool bk = (v) < td[k_];                          \
        bool bk1 = (v) < td[k_ - 1];                     \
        td[k_] = bk ? (bk1 ? td[k_ - 1] : (v)) : td[k_]; \
        ti[k_] = bk ? (bk1 ? ti[k_ - 1] : (idx)) : ti[k_]; \
      }                                                  \
      bool b0 = (v) < td[0];                             \
      ti[0] = b0 ? (idx) : ti[0];                        \
      td[0] = b0 ? (v) : td[0];                          \
    }                                                    \
  } while (0)

// ---------------- row sum of squares (float4) ----------------
__global__ __launch_bounds__(256) void k_rowsq(const float* __restrict__ a,
                                               float* __restrict__ out, int D) {
  int row = blockIdx.x;
  const float4* p = (const float4*)(a + (size_t)row * D);
  float s = 0.f;
  for (int d = threadIdx.x; d < (D >> 2); d += 256) {
    float4 v = p[d];
    s = fmaf(v.x, v.x, s); s = fmaf(v.y, v.y, s);
    s = fmaf(v.z, v.z, s); s = fmaf(v.w, v.w, s);
  }
#pragma unroll
  for (int m = 32; m; m >>= 1) s += __shfl_xor(s, m);
  __shared__ float red[4];
  int w = threadIdx.x >> 6;
  if ((threadIdx.x & 63) == 0) red[w] = s;
  __syncthreads();
  if (threadIdx.x == 0) out[row] = red[0] + red[1] + red[2] + red[3];
}

// ---------------- split fp32 into bf16 hi/lo ----------------
__global__ __launch_bounds__(256) void k_split(const float* __restrict__ a,
                                               ushort* __restrict__ hi,
                                               ushort* __restrict__ lo) {
  int idx = blockIdx.x * 256 + threadIdx.x;
  float4 v = ((const float4*)a)[idx];
  float vv[4] = {v.x, v.y, v.z, v.w};
  ushort h[4], l[4];
#pragma unroll
  for (int e = 0; e < 4; ++e) {
    h[e] = f2bf(vv[e]);
    l[e] = f2bf(vv[e] - bf2f(h[e]));
  }
  ushort4 hv; hv.x = h[0]; hv.y = h[1]; hv.z = h[2]; hv.w = h[3];
  ushort4 lv; lv.x = l[0]; lv.y = l[1]; lv.z = l[2]; lv.w = l[3];
  ((ushort4*)hi)[idx] = hv;
  ((ushort4*)lo)[idx] = lv;
}

// ---------------- kNN via MFMA: 128x128 tiles, register top-10 ----------------
struct SmemKNN {
  union {
    struct { ushort Ah[4096], Al[4096], Bh[4096], Bl[4096]; } s;  // 32 KB
    float D[128 * 129];                                           // 66 KB
  } u;
};

template<int PRE>
__global__ __launch_bounds__(256, 2) void k_knn(const float* __restrict__ x,
                                                const ushort* __restrict__ xh,
                                                const ushort* __restrict__ xl,
                                                const float* __restrict__ sqx,
                                                float* __restrict__ cand_d,
                                                int* __restrict__ cand_i) {
  __shared__ SmemKNN sm;
  const int strip = blockIdx.x;
  const int i0 = blockIdx.y * 128;
  const int tid = threadIdx.x;
  const int lane = tid & 63, wv = tid >> 6;
  const int wr = wv >> 1, wc = wv & 1;
  const int fr = lane & 15, fg = lane >> 4;

  // per-thread register top-10 over this thread's half-rows
  float td[KNN];
  int ti[KNN];
#pragma unroll
  for (int k = 0; k < KNN; ++k) { td[k] = 3.0e38f; ti[k] = 0; }
  const int srow = tid >> 1;          // scan row 0..127
  const int cbase = (tid & 1) * 64;   // half of the 128 cols

  for (int jt = 0; jt < SLEN / 128; ++jt) {
    const int j0 = strip * SLEN + jt * 128;
    f32x4 acc[4][4];
    const f32x4 zv = {0.f, 0.f, 0.f, 0.f};
#pragma unroll
    for (int m = 0; m < 4; ++m)
#pragma unroll
      for (int n = 0; n < 4; ++n) acc[m][n] = zv;

    for (int kc = 0; kc < DX; kc += 32) {
      __syncthreads();
      if (PRE) {
#pragma unroll
        for (int l = 0; l < 2; ++l) {
          int idx = tid + l * 256;            // 0..511
          int row = idx >> 2, c8 = idx & 3;   // 8 bf16 per c8
          int off = (row << 6) + (c8 << 4);
          off ^= (row & 7) << 4;
          size_t ga = (size_t)(i0 + row) * DX + kc + c8 * 8;
          size_t gb = (size_t)(j0 + row) * DX + kc + c8 * 8;
          *(uint4*)((char*)sm.u.s.Ah + off) = *(const uint4*)(xh + ga);
          *(uint4*)((char*)sm.u.s.Al + off) = *(const uint4*)(xl + ga);
          *(uint4*)((char*)sm.u.s.Bh + off) = *(const uint4*)(xh + gb);
          *(uint4*)((char*)sm.u.s.Bl + off) = *(const uint4*)(xl + gb);
        }
      } else {
#pragma unroll
        for (int l = 0; l < 4; ++l) {
          int idx = tid + l * 256;            // 0..1023
          int row = idx >> 3, c4 = idx & 7;
          int off = (row << 6) + (c4 << 3);
          off ^= (row & 7) << 4;
          float4 va = *(const float4*)&x[(size_t)(i0 + row) * DX + kc + c4 * 4];
          float4 vb = *(const float4*)&x[(size_t)(j0 + row) * DX + kc + c4 * 4];
          float av[4] = {va.x, va.y, va.z, va.w};
          float bv[4] = {vb.x, vb.y, vb.z, vb.w};
          ushort ah4[4], al4[4], bh4[4], bl4[4];
#pragma unroll
          for (int e = 0; e < 4; ++e) {
            ah4[e] = f2bf(av[e]); al4[e] = f2bf(av[e] - bf2f(ah4[e]));
            bh4[e] = f2bf(bv[e]); bl4[e] = f2bf(bv[e] - bf2f(bh4[e]));
          }
          uint2 p;
          p.x = (unsigned)ah4[0] | ((unsigned)ah4[1] << 16);
          p.y = (unsigned)ah4[2] | ((unsigned)ah4[3] << 16);
          *(uint2*)((char*)sm.u.s.Ah + off) = p;
          p.x = (unsigned)al4[0] | ((unsigned)al4[1] << 16);
          p.y = (unsigned)al4[2] | ((unsigned)al4[3] << 16);
          *(uint2*)((char*)sm.u.s.Al + off) = p;
          p.x = (unsigned)bh4[0] | ((unsigned)bh4[1] << 16);
          p.y = (unsigned)bh4[2] | ((unsigned)bh4[3] << 16);
          *(uint2*)((char*)sm.u.s.Bh + off) = p;
          p.x = (unsigned)bl4[0] | ((unsigned)bl4[1] << 16);
          p.y = (unsigned)bl4[2] | ((unsigned)bl4[3] << 16);
          *(uint2*)((char*)sm.u.s.Bl + off) = p;
        }
      }
      __syncthreads();
      short8v fah[4], fal[4];
#pragma unroll
      for (int m = 0; m < 4; ++m) {
        int r = wr * 64 + m * 16 + fr;
        fah[m] = frag_ld(sm.u.s.Ah, r, fg);
        fal[m] = frag_ld(sm.u.s.Al, r, fg);
      }
#pragma unroll
      for (int n = 0; n < 4; ++n) {
        int r = wc * 64 + n * 16 + fr;
        short8v fbh = frag_ld(sm.u.s.Bh, r, fg);
        short8v fbl = frag_ld(sm.u.s.Bl, r, fg);
#pragma unroll
        for (int m = 0; m < 4; ++m) {
          acc[m][n] = MFMA16(fah[m], fbh, acc[m][n]);
          acc[m][n] = MFMA16(fah[m], fbl, acc[m][n]);
          acc[m][n] = MFMA16(fal[m], fbh, acc[m][n]);
        }
      }
    }
    __syncthreads();
#pragma unroll
    for (int m = 0; m < 4; ++m)
#pragma unroll
      for (int n = 0; n < 4; ++n)
#pragma unroll
        for (int r = 0; r < 4; ++r) {
          int rl = wr * 64 + m * 16 + fg * 4 + r;
          int cl = wc * 64 + n * 16 + fr;
          int gi = i0 + rl, gj = j0 + cl;
          float v = sqx[gi] + sqx[gj] - 2.f * acc[m][n][r];
          sm.u.D[rl * 129 + cl] = (gi == gj) ? 3.0e38f : v;
        }
    __syncthreads();
    // register top-10 scan: 2 threads per row, 64 cols each
#pragma unroll 4
    for (int c = 0; c < 64; ++c) {
      float v = sm.u.D[srow * 129 + cbase + c];
      int idx = j0 + cbase + c;
      INSERT10(td, ti, v, idx);
    }
    // next jt's first __syncthreads() (inside kc loop) protects D from overwrite
  }
  {
    int row = i0 + srow;
    int slot = strip * 2 + (tid & 1);
#pragma unroll
    for (int l = 0; l < KNN; ++l) {
      cand_d[((size_t)row * NLIST + slot) * KNN + l] = td[l];
      cand_i[((size_t)row * NLIST + slot) * KNN + l] = ti[l];
    }
  }
}

// ---------------- merge candidates -> global top-10 (registers) ----------------
__global__ __launch_bounds__(64) void k_merge(const float* __restrict__ cand_d,
                                              const int* __restrict__ cand_i,
                                              int* __restrict__ knn) {
  int t = threadIdx.x;
  int row = blockIdx.x * 64 + t;
  float td[KNN]; int ti[KNN];
#pragma unroll
  for (int k = 0; k < KNN; ++k) { td[k] = 3.0e38f; ti[k] = 0; }
  const float* cd = cand_d + (size_t)row * NLIST * KNN;
  const int* ci = cand_i + (size_t)row * NLIST * KNN;
  for (int s = 0; s < NLIST; ++s)
    for (int l = 0; l < KNN; ++l) {
      float v = cd[s * KNN + l];
      int j = ci[s * KNN + l];
      INSERT10(td, ti, v, j);
    }
#pragma unroll
  for (int l = 0; l < KNN; ++l) knn[row * KNN + l] = ti[l];
}

// ---------------- Gram matrix of centered neighbors (one wave / point) ----
__global__ __launch_bounds__(64) void k_gram(const float* __restrict__ x,
                                             const int* __restrict__ knn,
                                             float* __restrict__ G) {
  const int pt = blockIdx.x;
  const int lane = threadIdx.x;
  const float4* nb[KNN];
#pragma unroll
  for (int a = 0; a < KNN; ++a)
    nb[a] = (const float4*)(x + (size_t)knn[pt * KNN + a] * DX);
  float P[55];
  float U[KNN];
  float q = 0.f;
#pragma unroll
  for (int c = 0; c < 55; ++c) P[c] = 0.f;
#pragma unroll
  for (int a = 0; a < KNN; ++a) U[a] = 0.f;
  for (int d4 = lane; d4 < DX / 4; d4 += 64) {
    float4 n4[KNN];
#pragma unroll
    for (int a = 0; a < KNN; ++a) n4[a] = nb[a][d4];
#pragma unroll
    for (int e = 0; e < 4; ++e) {
      float n[KNN];
#pragma unroll
      for (int a = 0; a < KNN; ++a) n[a] = ((const float*)&n4[a])[e];
      float m = 0.f;
#pragma unroll
      for (int a = 0; a < KNN; ++a) m += n[a];
      m *= 0.1f;
      q = fmaf(m, m, q);
#pragma unroll
      for (int a = 0; a < KNN; ++a) U[a] = fmaf(n[a], m, U[a]);
      int c = 0;
#pragma unroll
      for (int a = 0; a < KNN; ++a)
#pragma unroll
        for (int b = a; b < KNN; ++b) { P[c] = fmaf(n[a], n[b], P[c]); ++c; }
    }
  }
#pragma unroll
  for (int c = 0; c < 55; ++c)
#pragma unroll
    for (int m2 = 32; m2; m2 >>= 1) P[c] += __shfl_xor(P[c], m2);
#pragma unroll
  for (int a = 0; a < KNN; ++a)
#pragma unroll
    for (int m2 = 32; m2; m2 >>= 1) U[a] += __shfl_xor(U[a], m2);
#pragma unroll
  for (int m2 = 32; m2; m2 >>= 1) q += __shfl_xor(q, m2);
  if (lane == 0) {
    int c = 0;
    for (int a = 0; a < KNN; ++a)
      for (int b = a; b < KNN; ++b) { G[(size_t)pt * 55 + c] = P[c] - U[a] - U[b] + q; ++c; }
  }
}

// ---------------- Jacobi eigenvalues of 10x10 in registers ---------------
__device__ __forceinline__ constexpr int IJ(int a, int b) {
  return (a <= b) ? (10 * a - (a * (a - 1)) / 2 + (b - a))
                  : (10 * b - (b * (b - 1)) / 2 + (a - b));
}

#define NSWEEP 6
__global__ __launch_bounds__(64) void k_jacobi(const float* __restrict__ G,
                                               float* __restrict__ curv) {
  const int pt = blockIdx.x * 64 + threadIdx.x;
  float M[55];
#pragma unroll
  for (int c = 0; c < 55; ++c) M[c] = G[(size_t)pt * 55 + c];

#pragma unroll
  for (int sweep = 0; sweep < NSWEEP; ++sweep) {
#pragma unroll
    for (int p = 0; p < KNN - 1; ++p) {
#pragma unroll
      for (int q = p + 1; q < KNN; ++q) {
        float apq = M[IJ(p, q)];
        float app = M[IJ(p, p)], aqq = M[IJ(q, q)];
        float theta = (aqq - app) / (2.f * apq);
        float t = 1.f / (fabsf(theta) + sqrtf(fmaf(theta, theta, 1.f)));
        t = (theta < 0.f) ? -t : t;
        t = (apq == 0.f) ? 0.f : t;
        float cc = 1.f / sqrtf(fmaf(t, t, 1.f));
        float ss = t * cc;
#pragma unroll
        for (int r = 0; r < KNN; ++r) {
          if (r == p || r == q) continue;
          float vrp = M[IJ(r, p)];
          float vrq = M[IJ(r, q)];
          M[IJ(r, p)] = cc * vrp - ss * vrq;
          M[IJ(r, q)] = ss * vrp + cc * vrq;
        }
        M[IJ(p, p)] = app - t * apq;
        M[IJ(q, q)] = aqq + t * apq;
        M[IJ(p, q)] = 0.f;
      }
    }
  }

  float lmax = 0.f, ssum = 0.f;
#pragma unroll
  for (int a = 0; a < KNN; ++a) {
    float l = fmaxf(M[IJ(a, a)], 0.f);
    lmax = fmaxf(lmax, l);
    ssum += sqrtf(l);
  }
  curv[pt] = 1.f - sqrtf(lmax) / (ssum + 1e-8f);
}

// ---------------- fused z/ref upper-triangle pass (MFMA) ----------------
template<int PRE>
__global__ __launch_bounds__(256, 2) void k_zr(const float* __restrict__ z,
                                               const float* __restrict__ rfm,
                                               const ushort* __restrict__ zh,
                                               const ushort* __restrict__ zl,
                                               const ushort* __restrict__ rh,
                                               const ushort* __restrict__ rl,
                                               const float* __restrict__ sqz,
                                               const float* __restrict__ sqr,
                                               const float* __restrict__ curv,
                                               double* __restrict__ pS,
                                               float* __restrict__ pM) {
  __shared__ struct { ushort Ah[4096], Al[4096], Bh[4096], Bl[4096]; } s;
  const int t = blockIdx.x;
  int ib = 0, base = 0;
  while (base + (32 - ib) <= t) { base += 32 - ib; ++ib; }
  const int jb = ib + (t - base);
  const int i0 = ib * 128, j0 = jb * 128;
  const int tid = threadIdx.x;
  const int lane = tid & 63, wv = tid >> 6;
  const int wr = wv >> 1, wc = wv & 1;
  const int fr = lane & 15, fg = lane >> 4;

  f32x4 zacc[4][4], racc[4][4];
  const f32x4 zv = {0.f, 0.f, 0.f, 0.f};
#pragma unroll
  for (int m = 0; m < 4; ++m)
#pragma unroll
    for (int n = 0; n < 4; ++n) { zacc[m][n] = zv; racc[m][n] = zv; }

#pragma unroll
  for (int mat = 0; mat < 2; ++mat) {
    const float* P = mat ? rfm : z;
    const ushort* Ph = mat ? rh : zh;
    const ushort* Pl = mat ? rl : zl;
    for (int kc = 0; kc < DZ; kc += 32) {
      __syncthreads();
      if (PRE) {
#pragma unroll
        for (int l = 0; l < 2; ++l) {
          int idx = tid + l * 256;
          int row = idx >> 2, c8 = idx & 3;
          int off = (row << 6) + (c8 << 4);
          off ^= (row & 7) << 4;
          size_t ga = (size_t)(i0 + row) * DZ + kc + c8 * 8;
          size_t gb = (size_t)(j0 + row) * DZ + kc + c8 * 8;
          *(uint4*)((char*)s.Ah + off) = *(const uint4*)(Ph + ga);
          *(uint4*)((char*)s.Al + off) = *(const uint4*)(Pl + ga);
          *(uint4*)((char*)s.Bh + off) = *(const uint4*)(Ph + gb);
          *(uint4*)((char*)s.Bl + off) = *(const uint4*)(Pl + gb);
        }
      } else {
#pragma unroll
        for (int l = 0; l < 4; ++l) {
          int idx = tid + l * 256;
          int row = idx >> 3, c4 = idx & 7;
          int off = (row << 6) + (c4 << 3);
          off ^= (row & 7) << 4;
          float4 va = *(const float4*)&P[(size_t)(i0 + row) * DZ + kc + c4 * 4];
          float4 vb = *(const float4*)&P[(size_t)(j0 + row) * DZ + kc + c4 * 4];
          float av[4] = {va.x, va.y, va.z, va.w};
          float bv[4] = {vb.x, vb.y, vb.z, vb.w};
          ushort ah4[4], al4[4], bh4[4], bl4[4];
#pragma unroll
          for (int e = 0; e < 4; ++e) {
            ah4[e] = f2bf(av[e]); al4[e] = f2bf(av[e] - bf2f(ah4[e]));
            bh4[e] = f2bf(bv[e]); bl4[e] = f2bf(bv[e] - bf2f(bh4[e]));
          }
          uint2 p;
          p.x = (unsigned)ah4[0] | ((unsigned)ah4[1] << 16);
          p.y = (unsigned)ah4[2] | ((unsigned)ah4[3] << 16);
          *(uint2*)((char*)s.Ah + off) = p;
          p.x = (unsigned)al4[0] | ((unsigned)al4[1] << 16);
          p.y = (unsigned)al4[2] | ((unsigned)al4[3] << 16);
          *(uint2*)((char*)s.Al + off) = p;
          p.x = (unsigned)bh4[0] | ((unsigned)bh4[1] << 16);
          p.y = (unsigned)bh4[2] | ((unsigned)bh4[3] << 16);
          *(uint2*)((char*)s.Bh + off) = p;
          p.x = (unsigned)bl4[0] | ((unsigned)bl4[1] << 16);
          p.y = (unsigned)bl4[2] | ((unsigned)bl4[3] << 16);
          *(uint2*)((char*)s.Bl + off) = p;
        }
      }
      __syncthreads();
      short8v fah[4], fal[4];
#pragma unroll
      for (int m = 0; m < 4; ++m) {
        int r = wr * 64 + m * 16 + fr;
        fah[m] = frag_ld(s.Ah, r, fg);
        fal[m] = frag_ld(s.Al, r, fg);
      }
#pragma unroll
      for (int n = 0; n < 4; ++n) {
        int r = wc * 64 + n * 16 + fr;
        short8v fbh = frag_ld(s.Bh, r, fg);
        short8v fbl = frag_ld(s.Bl, r, fg);
#pragma unroll
        for (int m = 0; m < 4; ++m) {
          if (mat == 0) {
            zacc[m][n] = MFMA16(fah[m], fbh, zacc[m][n]);
            zacc[m][n] = MFMA16(fah[m], fbl, zacc[m][n]);
            zacc[m][n] = MFMA16(fal[m], fbh, zacc[m][n]);
          } else {
            racc[m][n] = MFMA16(fah[m], fbh, racc[m][n]);
            racc[m][n] = MFMA16(fah[m], fbl, racc[m][n]);
            racc[m][n] = MFMA16(fal[m], fbh, racc[m][n]);
          }
        }
      }
    }
  }

  double s1 = 0, s2 = 0, s3 = 0;
  float mz = 0.f, mr = 0.f;
#pragma unroll
  for (int m = 0; m < 4; ++m)
#pragma unroll
    for (int n = 0; n < 4; ++n)
#pragma unroll
      for (int r = 0; r < 4; ++r) {
        int gi = i0 + wr * 64 + m * 16 + fg * 4 + r;
        int gj = j0 + wc * 64 + n * 16 + fr;
        if (gj > gi) {
          float z2 = fmaxf(sqz[gi] + sqz[gj] - 2.f * zacc[m][n][r], 0.f);
          float r2 = fmaxf(sqr[gi] + sqr[gj] - 2.f * racc[m][n][r], 0.f);
          float w = fmaxf(1.f - fmaxf(curv[gi], curv[gj]), 0.1f);
          s1 += (double)(w * z2);
          s3 += (double)(w * r2);
          s2 += (double)(w * sqrtf(z2 * r2));
          mz = fmaxf(mz, z2);
          mr = fmaxf(mr, r2);
        }
      }
#pragma unroll
  for (int m = 32; m; m >>= 1) {
    s1 += __shfl_xor(s1, m);
    s2 += __shfl_xor(s2, m);
    s3 += __shfl_xor(s3, m);
    mz = fmaxf(mz, __shfl_xor(mz, m));
    mr = fmaxf(mr, __shfl_xor(mr, m));
  }
  __shared__ double rd[4][3];
  __shared__ float rf2[4][2];
  int w = tid >> 6;
  if ((tid & 63) == 0) { rd[w][0] = s1; rd[w][1] = s2; rd[w][2] = s3; rf2[w][0] = mz; rf2[w][1] = mr; }
  __syncthreads();
  if (tid == 0) {
    double a = 0, b = 0, c = 0; float d = 0.f, e = 0.f;
    for (int i = 0; i < 4; ++i) {
      a += rd[i][0]; b += rd[i][1]; c += rd[i][2];
      d = fmaxf(d, rf2[i][0]); e = fmaxf(e, rf2[i][1]);
    }
    pS[(size_t)t * 3 + 0] = a; pS[(size_t)t * 3 + 1] = b; pS[(size_t)t * 3 + 2] = c;
    pM[(size_t)t * 2 + 0] = d; pM[(size_t)t * 2 + 1] = e;
  }
}

// ---------------- final combine ----------------
__global__ __launch_bounds__(256) void k_final(const double* __restrict__ pS,
                                               const float* __restrict__ pM,
                                               int nb, float* __restrict__ out) {
  int tid = threadIdx.x;
  double s1 = 0, s2 = 0, s3 = 0; float mz = 0.f, mr = 0.f;
  for (int i = tid; i < nb; i += 256) {
    s1 += pS[(size_t)i * 3 + 0]; s2 += pS[(size_t)i * 3 + 1]; s3 += pS[(size_t)i * 3 + 2];
    mz = fmaxf(mz, pM[(size_t)i * 2 + 0]); mr = fmaxf(mr, pM[(size_t)i * 2 + 1]);
  }
#pragma unroll
  for (int m = 32; m; m >>= 1) {
    s1 += __shfl_xor(s1, m); s2 += __shfl_xor(s2, m); s3 += __shfl_xor(s3, m);
    mz = fmaxf(mz, __shfl_xor(mz, m)); mr = fmaxf(mr, __shfl_xor(mr, m));
  }
  __shared__ double rd[4][3];
  __shared__ float rf2[4][2];
  int w = tid >> 6;
  if ((tid & 63) == 0) { rd[w][0] = s1; rd[w][1] = s2; rd[w][2] = s3; rf2[w][0] = mz; rf2[w][1] = mr; }
  __syncthreads();
  if (tid == 0) {
    double a = 0, b = 0, c = 0; float d = 0.f, e = 0.f;
    for (int i = 0; i < 4; ++i) {
      a += rd[i][0]; b += rd[i][1]; c += rd[i][2];
      d = fmaxf(d, rf2[i][0]); e = fmaxf(e, rf2[i][1]);
    }
    double zm = sqrt((double)d) + 1e-8;
    double rm = sqrt((double)e) + 1e-8;
    double total = a / (zm * zm) - 2.0 * b / (zm * rm) + c / (rm * rm);
    double npairs = (double)NB * (double)(NB - 1) / 2.0;
    out[0] = (float)(total / npairs);
  }
}

extern "C" void kernel_launch(void* const* d_in, const int* in_sizes, int n_in,
                              void* d_out, int out_size, void* d_ws, size_t ws_size,
                              hipStream_t stream) {
  const float* z = (const float*)d_in[0];
  const float* rfm = (const float*)d_in[1];
  const float* x = (const float*)d_in[2];
  float* out = (float*)d_out;
  char* w = (char*)d_ws;

  float*  sqx    = (float*)(w + 0);                    // 16 KB
  float*  sqz    = (float*)(w + 16384);
  float*  sqr    = (float*)(w + 32768);
  float*  curv   = (float*)(w + 49152);
  int*    knn    = (int*)(w + 65536);                  // 160 KB
  float*  cand_d = (float*)(w + 229376);               // 5.24 MB
  int*    cand_i = (int*)(w + 5472256);                // 5.24 MB
  float*  G      = (float*)(w + 10715136);             // 900 KB
  double* pS     = (double*)(w + 11616256);            // 12.7 KB
  float*  pM     = (float*)(w + 11628928);             // 4.2 KB

  ushort* xh = (ushort*)(w + (size_t)12 * 1024 * 1024); // 8 MB
  ushort* xl = (ushort*)(w + (size_t)20 * 1024 * 1024); // 8 MB
  ushort* zh = (ushort*)(w + (size_t)28 * 1024 * 1024); // 1 MB
  ushort* zl = (ushort*)(w + (size_t)29 * 1024 * 1024); // 1 MB
  ushort* rh = (ushort*)(w + (size_t)30 * 1024 * 1024); // 1 MB
  ushort* rl = (ushort*)(w + (size_t)31 * 1024 * 1024); // 1 MB
  const bool pre = ws_size >= (size_t)32 * 1024 * 1024;

  k_rowsq<<<NB, 256, 0, stream>>>(x, sqx, DX);
  k_rowsq<<<NB, 256, 0, stream>>>(z, sqz, DZ);
  k_rowsq<<<NB, 256, 0, stream>>>(rfm, sqr, DZ);
  if (pre) {
    k_split<<<NB * DX / 4 / 256, 256, 0, stream>>>(x, xh, xl);
    k_split<<<NB * DZ / 4 / 256, 256, 0, stream>>>(z, zh, zl);
    k_split<<<NB * DZ / 4 / 256, 256, 0, stream>>>(rfm, rh, rl);
    k_knn<1><<<dim3(STR, NB / 128), 256, 0, stream>>>(x, xh, xl, sqx, cand_d, cand_i);
  } else {
    k_knn<0><<<dim3(STR, NB / 128), 256, 0, stream>>>(x, xh, xl, sqx, cand_d, cand_i);
  }
  k_merge<<<NB / 64, 64, 0, stream>>>(cand_d, cand_i, knn);
  k_gram<<<NB, 64, 0, stream>>>(x, knn, G);
  k_jacobi<<<NB / 64, 64, 0, stream>>>(G, curv);
  if (pre) {
    k_zr<1><<<528, 256, 0, stream>>>(z, rfm, zh, zl, rh, rl, sqz, sqr, curv, pS, pM);
  } else {
    k_zr<0><<<528, 256, 0, stream>>>(z, rfm, zh, zl, rh, rl, sqz, sqr, curv, pS, pM);
  }
  k_final<<<1, 256, 0, stream>>>(pS, pM, 528, out);
}